// Round 3
// baseline (526.773 us; speedup 1.0000x reference)
//
#include <hip/hip_runtime.h>
#include <hip/hip_bf16.h>

// Problem constants: B=256, N=128, EB=5, NA=64, DIM=512, NIT=3
// out = [logit (256 f32), graph_repr (256*512 f32)]

typedef __bf16 bf16;
typedef __bf16 bf16x4 __attribute__((ext_vector_type(4)));
typedef __bf16 bf16x8 __attribute__((ext_vector_type(8)));
typedef float floatx4 __attribute__((ext_vector_type(4)));

__device__ __forceinline__ void glds16(const void* g, void* l) {
    __builtin_amdgcn_global_load_lds((const __attribute__((address_space(1))) unsigned int*)g,
                                     (__attribute__((address_space(3))) unsigned int*)l,
                                     16, 0, 0);
}

// ---------------------------------------------------------------- convert node f32 -> bf16, 8/thread
__global__ __launch_bounds__(256) void k_cvt_node(const float* __restrict__ in,
                                                  bf16* __restrict__ out) {
    int i = (blockIdx.x * 256 + threadIdx.x) * 8;
    float4 a = *(const float4*)(in + i);
    float4 b = *(const float4*)(in + i + 4);
    bf16x8 v;
    v[0] = (bf16)a.x; v[1] = (bf16)a.y; v[2] = (bf16)a.z; v[3] = (bf16)a.w;
    v[4] = (bf16)b.x; v[5] = (bf16)b.y; v[6] = (bf16)b.z; v[7] = (bf16)b.w;
    *(bf16x8*)(out + i) = v;
}

// ---------------------------------------------------------------- Ahat[b,n,m] = sum_e adj[...,1:] + (n==m)
__global__ __launch_bounds__(256) void k_asum(const float* __restrict__ adj,
                                              bf16* __restrict__ ahat) {
    int i = blockIdx.x * 256 + threadIdx.x;   // group of 4 elements
    int base = i * 4;
    const float4* p = (const float4*)(adj + (size_t)base * 5);
    float4 v0 = p[0], v1 = p[1], v2 = p[2], v3 = p[3], v4 = p[4];
    float s[4];
    s[0] = v0.y + v0.z + v0.w + v1.x;
    s[1] = v1.z + v1.w + v2.x + v2.y;
    s[2] = v2.w + v3.x + v3.y + v3.z;
    s[3] = v4.x + v4.y + v4.z + v4.w;
    bf16x4 o;
#pragma unroll
    for (int j = 0; j < 4; j++) {
        int e = base + j;
        int m = e & 127, n = (e >> 7) & 127;
        float v = s[j] + ((n == m) ? 1.0f : 0.0f);
        o[j] = (bf16)v;
    }
    *(bf16x4*)(ahat + base) = o;
}

// ---------------------------------------------------------------- transpose [R,C] -> [C,R], out bf16 (weights only)
template <typename Tin>
__global__ __launch_bounds__(256) void k_transpose(const Tin* __restrict__ in, bf16* __restrict__ out,
                                                   int R, int C, long long sIn, long long sOut) {
    __shared__ bf16 tile[32][33];
    const Tin* src = in + (size_t)blockIdx.z * sIn;
    bf16* dst = out + (size_t)blockIdx.z * sOut;
    int c0 = blockIdx.x * 32, r0 = blockIdx.y * 32;
    int tx = threadIdx.x & 31, ty = threadIdx.x >> 5;
#pragma unroll
    for (int i = 0; i < 4; i++) {
        int r = ty + i * 8;
        tile[r][tx] = (bf16)(float)src[(size_t)(r0 + r) * C + c0 + tx];
    }
    __syncthreads();
#pragma unroll
    for (int i = 0; i < 4; i++) {
        int c = ty + i * 8;
        dst[(size_t)(c0 + c) * R + r0 + tx] = tile[tx][c];
    }
}

// ---------------------------------------------------------------- fused WLS forward: embed + 3x(agg, linear)
// One block per batch. hT global buffer [256][512 d][128 n] is in/out (in-place per iteration).
// Ts (LDS) holds t[n=128][d=512], 16B-chunk-swizzled: phys_chunk = chunk ^ (n & 15).
// Sb (LDS) double-buffers 32-row h^T staging chunks [32 d][128 m], swizzle chunk ^ (row & 15).
__global__ __launch_bounds__(256) void k_mega(
    const bf16* __restrict__ nodeb,   // [256][128][64]
    const bf16* __restrict__ Web_t,   // [512][64]
    const float* __restrict__ b_embed,// [512]
    const bf16* __restrict__ Ahat,    // [256][128][128]
    const bf16* __restrict__ Wlb_t,   // [3][512][512] (W^T per layer)
    const float* __restrict__ b_layers,// [3][512]
    bf16* __restrict__ hT)            // [256][512][128]
{
    __shared__ __align__(16) bf16 Ts[128 * 512];   // 131072 B
    __shared__ __align__(16) bf16 Sb[2][32 * 128]; // 2 x 8192 B

    const int b = blockIdx.x;
    const int tid = threadIdx.x;
    const int lane = tid & 63, w = tid >> 6;
    const int q = lane >> 4, l16 = lane & 15;
    const int wm = w >> 1, wn = w & 1;

    bf16* hTb = hT + (size_t)b * 65536;

    // ---------------- embed: h0^T = (node @ W_embed + b_embed)^T
    {
        const bf16* Ab = nodeb + (size_t)b * 8192;
        for (int dc = 0; dc < 4; dc++) {
            floatx4 acc[4][4] = {};
#pragma unroll
            for (int ks = 0; ks < 2; ks++) {
                bf16x8 af[4], bfr[4];
#pragma unroll
                for (int mt = 0; mt < 4; mt++)
                    af[mt] = *(const bf16x8*)(Ab + (wm * 64 + mt * 16 + l16) * 64 + ks * 32 + q * 8);
#pragma unroll
                for (int nt = 0; nt < 4; nt++)
                    bfr[nt] = *(const bf16x8*)(Web_t + (size_t)(dc * 128 + wn * 64 + nt * 16 + l16) * 64 + ks * 32 + q * 8);
#pragma unroll
                for (int mt = 0; mt < 4; mt++)
#pragma unroll
                    for (int nt = 0; nt < 4; nt++)
                        acc[mt][nt] = __builtin_amdgcn_mfma_f32_16x16x32_bf16(af[mt], bfr[nt], acc[mt][nt], 0, 0, 0);
            }
#pragma unroll
            for (int mt = 0; mt < 4; mt++)
#pragma unroll
                for (int nt = 0; nt < 4; nt++) {
                    int dp = dc * 128 + wn * 64 + nt * 16 + l16;
                    float bv = b_embed[dp];
                    int n0 = wm * 64 + mt * 16 + q * 4;
                    bf16x4 pk;
#pragma unroll
                    for (int r = 0; r < 4; r++) pk[r] = (bf16)(acc[mt][nt][r] + bv);
                    *(bf16x4*)(hTb + (size_t)dp * 128 + n0) = pk;
                }
        }
    }
    __threadfence();
    __syncthreads();

    // ---------------- 3 WLS iterations
    for (int it = 0; it < 3; it++) {
        const bf16* WT = Wlb_t + (size_t)it * 262144;
        const float* bl = b_layers + it * 512;

        // Ahat B-frags in registers: n = w*32 + ntl*16 + l16
        bf16x8 ah[2][4];
#pragma unroll
        for (int ntl = 0; ntl < 2; ntl++)
#pragma unroll
            for (int kk = 0; kk < 4; kk++)
                ah[ntl][kk] = *(const bf16x8*)(Ahat + (size_t)b * 16384 +
                                               (size_t)(w * 32 + ntl * 16 + l16) * 128 + kk * 32 + q * 8);

        // ----- phase 1: Ts[n][d] = Ahat @ h  (M=d, N=n, K=m)
        {
            // stage(dc, buf): [32 d][128 m] via glds, 2 slots/thread
            auto stage = [&](int dc, int buf) {
#pragma unroll
                for (int s = 0; s < 2; s++) {
                    int p = s * 256 + w * 64 + lane;
                    int r = p >> 4, c = p & 15;
                    int l = c ^ (r & 15);
                    glds16(hTb + (size_t)(dc * 32 + r) * 128 + l * 8,
                           (char*)Sb[buf] + (size_t)(s * 256 + w * 64) * 16);
                }
            };
            stage(0, 0);
            for (int dc = 0; dc < 16; dc++) {
                __syncthreads();
                if (dc + 1 < 16) stage(dc + 1, (dc + 1) & 1);
                const bf16* S = Sb[dc & 1];
                bf16x8 af[2][4];
#pragma unroll
                for (int mtl = 0; mtl < 2; mtl++)
#pragma unroll
                    for (int kk = 0; kk < 4; kk++) {
                        int r = mtl * 16 + l16;
                        int c = kk * 4 + q;
                        af[mtl][kk] = *(const bf16x8*)(S + r * 128 + (c ^ (r & 15)) * 8);
                    }
                floatx4 acc[2][2] = {};
#pragma unroll
                for (int kk = 0; kk < 4; kk++)
#pragma unroll
                    for (int mtl = 0; mtl < 2; mtl++)
#pragma unroll
                        for (int ntl = 0; ntl < 2; ntl++)
                            acc[mtl][ntl] = __builtin_amdgcn_mfma_f32_16x16x32_bf16(
                                af[mtl][kk], ah[ntl][kk], acc[mtl][ntl], 0, 0, 0);
#pragma unroll
                for (int mtl = 0; mtl < 2; mtl++)
#pragma unroll
                    for (int ntl = 0; ntl < 2; ntl++) {
                        int n = w * 32 + ntl * 16 + l16;
                        int d0 = dc * 32 + mtl * 16 + q * 4;
                        int c = d0 >> 3;
                        bf16x4 pk;
#pragma unroll
                        for (int r = 0; r < 4; r++) pk[r] = (bf16)acc[mtl][ntl][r];
                        *(bf16x4*)&Ts[n * 512 + (c ^ (n & 15)) * 8 + (d0 & 7)] = pk;
                    }
            }
            __syncthreads();
        }

        // ----- phase 2: h'^T = relu(t @ W + b)^T  (M=n, N=d', K=d), barrier-free K sweep
        for (int dc = 0; dc < 4; dc++) {
            floatx4 acc[4][4] = {};
            bf16x8 bpf[3][4], apf[2][4];
            auto loadB = [&](int ks, bf16x8* dst) {
#pragma unroll
                for (int nt = 0; nt < 4; nt++) {
                    int dp = dc * 128 + wn * 64 + nt * 16 + l16;
                    dst[nt] = *(const bf16x8*)(WT + (size_t)dp * 512 + ks * 32 + q * 8);
                }
            };
            auto loadA = [&](int ks, bf16x8* dst) {
#pragma unroll
                for (int mt = 0; mt < 4; mt++) {
                    int n = wm * 64 + mt * 16 + l16;
                    int c = ks * 4 + q;
                    dst[mt] = *(const bf16x8*)&Ts[n * 512 + (c ^ (n & 15)) * 8];
                }
            };
            loadB(0, bpf[0]);
            loadB(1, bpf[1]);
            loadA(0, apf[0]);
#pragma unroll
            for (int ks = 0; ks < 16; ks++) {
                if (ks + 2 < 16) loadB(ks + 2, bpf[(ks + 2) % 3]);
                if (ks + 1 < 16) loadA(ks + 1, apf[(ks + 1) & 1]);
#pragma unroll
                for (int mt = 0; mt < 4; mt++)
#pragma unroll
                    for (int nt = 0; nt < 4; nt++)
                        acc[mt][nt] = __builtin_amdgcn_mfma_f32_16x16x32_bf16(
                            apf[ks & 1][mt], bpf[ks % 3][nt], acc[mt][nt], 0, 0, 0);
            }
#pragma unroll
            for (int mt = 0; mt < 4; mt++)
#pragma unroll
                for (int nt = 0; nt < 4; nt++) {
                    int dp = dc * 128 + wn * 64 + nt * 16 + l16;
                    float bv = bl[dp];
                    int n0 = wm * 64 + mt * 16 + q * 4;
                    bf16x4 pk;
#pragma unroll
                    for (int r = 0; r < 4; r++) {
                        float v = acc[mt][nt][r] + bv;
                        pk[r] = (bf16)fmaxf(v, 0.f);
                    }
                    *(bf16x4*)(hTb + (size_t)dp * 128 + n0) = pk;
                }
        }
        __threadfence();
        __syncthreads();
    }
}

// ---------------------------------------------------------------- mean over nodes + logit, from h^T [B][512][128]
__global__ __launch_bounds__(256) void k_finalize(const bf16* __restrict__ ht,
                                                  const float* __restrict__ W_out,
                                                  const float* __restrict__ b_out,
                                                  float* __restrict__ out) {
    int b = blockIdx.x, t = threadIdx.x;
    const bf16* hb = ht + (size_t)b * 65536;
    float partial = 0.f;
#pragma unroll
    for (int j = 0; j < 2; j++) {
        int d = t + j * 256;
        const bf16* p = hb + (size_t)d * 128;
        float s = 0.f;
        for (int i = 0; i < 128; i += 8) {
            bf16x8 v = *(const bf16x8*)&p[i];
#pragma unroll
            for (int k = 0; k < 8; k++) s += (float)v[k];
        }
        float g = s * (1.f / 128.f);
        out[256 + (size_t)b * 512 + d] = g;
        partial += g * W_out[d];
    }
    __shared__ float red[256];
    red[t] = partial;
    __syncthreads();
    for (int s = 128; s > 0; s >>= 1) {
        if (t < s) red[t] += red[t + s];
        __syncthreads();
    }
    if (t == 0) out[b] = red[0] + b_out[0];
}

// ---------------------------------------------------------------- launch
extern "C" void kernel_launch(void* const* d_in, const int* in_sizes, int n_in,
                              void* d_out, int out_size, void* d_ws, size_t ws_size,
                              hipStream_t stream) {
    const float* adj      = (const float*)d_in[0];
    // d_in[1] = hidden (unused by forward)
    const float* node     = (const float*)d_in[2];
    const float* W_embed  = (const float*)d_in[3];
    const float* b_embed  = (const float*)d_in[4];
    const float* W_layers = (const float*)d_in[5];
    const float* b_layers = (const float*)d_in[6];
    const float* W_out    = (const float*)d_in[7];
    const float* b_out    = (const float*)d_in[8];
    float* out = (float*)d_out;

    char* ws = (char*)d_ws;
    bf16* nodeb = (bf16*)(ws);              //  4,194,304 B : node bf16 [256][128][64]
    bf16* Web_t = (bf16*)(ws + 4194304);    //     65,536 B : W_embed^T bf16 [512][64]
    bf16* Wlb_t = (bf16*)(ws + 4259840);    //  1,572,864 B : W_layers^T bf16 [3][512][512]
    bf16* Ahat  = (bf16*)(ws + 5832704);    //  8,388,608 B : (Asum + I) [256][128][128]
    bf16* h_t   = (bf16*)(ws + 14221312);   // 33,554,432 B : h^T [256][512][128]  (end 47.8 MB)

    k_cvt_node<<<1024, 256, 0, stream>>>(node, nodeb);
    k_transpose<float><<<dim3(16, 2, 1), 256, 0, stream>>>(W_embed, Web_t, 64, 512, 0, 0);
    k_transpose<float><<<dim3(16, 16, 3), 256, 0, stream>>>(W_layers, Wlb_t, 512, 512, 262144, 262144);
    k_asum<<<4096, 256, 0, stream>>>(adj, Ahat);
    k_mega<<<256, 256, 0, stream>>>(nodeb, Web_t, b_embed, Ahat, Wlb_t, b_layers, h_t);
    k_finalize<<<256, 256, 0, stream>>>(h_t, W_out, b_out, out);
}